// Round 2
// baseline (522.432 us; speedup 1.0000x reference)
//
#include <hip/hip_runtime.h>

#define KC 64   // clusters
#define DD 64   // dims

// ws layout (floats): [0..63] colsum, [64..127] distsum, [128..191] counts, [192] sep_sum

__global__ __launch_bounds__(256, 8) void aux_main(
    const float* __restrict__ z,
    const float* __restrict__ assign,
    const float* __restrict__ centers,
    float* __restrict__ ws, int B)
{
    __shared__ float s_c[KC * DD];     // centers fp32, 16 KB
    __shared__ float s_colsum[KC];
    __shared__ float s_dist[KC];
    __shared__ float s_cnt[KC];

    const int tid = threadIdx.x;

    // stage centers: 4096 floats = 1024 float4
    {
        const float4* c4 = (const float4*)centers;
        float4* s4 = (float4*)s_c;
        for (int i = tid; i < KC * DD / 4; i += 256) s4[i] = c4[i];
    }
    if (tid < KC) { s_colsum[tid] = 0.f; s_dist[tid] = 0.f; s_cnt[tid] = 0.f; }
    __syncthreads();

    const int wave   = tid >> 6;
    const int lane   = tid & 63;
    const int subrow = lane >> 4;   // 0..3 : which of 4 rows this wave-iter
    const int sub    = lane & 15;   // 0..15: 16 lanes cover one 64-col row (float4 each)

    const int gw   = blockIdx.x * 4 + wave;
    const int nw   = gridDim.x * 4;
    const int ngrp = (B + 3) >> 2;

    float cs0 = 0.f, cs1 = 0.f, cs2 = 0.f, cs3 = 0.f;

    for (int g = gw; g < ngrp; g += nw) {
        int r = g * 4 + subrow;
        if (r < B) {
            size_t off = (size_t)r * DD + sub * 4;

            float4 a = *(const float4*)(assign + off);
            cs0 += a.x; cs1 += a.y; cs2 += a.z; cs3 += a.w;

            // in-lane argmax, first index wins (strict >)
            float m = a.x; int mi = 0;
            if (a.y > m) { m = a.y; mi = 1; }
            if (a.z > m) { m = a.z; mi = 2; }
            if (a.w > m) { m = a.w; mi = 3; }
            mi += sub * 4;

            // reduce across 16-lane subgroup; ties -> lowest index (np.argmax)
            #pragma unroll
            for (int d = 1; d < 16; d <<= 1) {
                float om  = __shfl_xor(m, d, 16);
                int   omi = __shfl_xor(mi, d, 16);
                if (om > m || (om == m && omi < mi)) { m = om; mi = omi; }
            }
            const int hard = mi;

            float4 zv = *(const float4*)(z + off);
            const float* cp = &s_c[hard * DD + sub * 4];
            float d0 = zv.x - cp[0], d1 = zv.y - cp[1];
            float d2 = zv.z - cp[2], d3 = zv.w - cp[3];
            float ss = d0*d0 + d1*d1 + d2*d2 + d3*d3;

            #pragma unroll
            for (int d = 1; d < 16; d <<= 1) ss += __shfl_xor(ss, d, 16);

            if (sub == 0) {
                atomicAdd(&s_dist[hard], ss > 0.f ? sqrtf(ss) : 0.f);
                atomicAdd(&s_cnt[hard], 1.f);
            }
        }
    }

    atomicAdd(&s_colsum[sub * 4 + 0], cs0);
    atomicAdd(&s_colsum[sub * 4 + 1], cs1);
    atomicAdd(&s_colsum[sub * 4 + 2], cs2);
    atomicAdd(&s_colsum[sub * 4 + 3], cs3);
    __syncthreads();

    if (tid < KC) {
        atomicAdd(&ws[tid],       s_colsum[tid]);
        atomicAdd(&ws[64 + tid],  s_dist[tid]);
        atomicAdd(&ws[128 + tid], s_cnt[tid]);
    }
}

// one block per center row i; thread j computes ||c_i - c_j|| (j != i)
__global__ void aux_sep(const float* __restrict__ centers, float* __restrict__ ws)
{
    __shared__ float rowi[DD];
    const int i = blockIdx.x;
    const int j = threadIdx.x;

    if (j < 16) ((float4*)rowi)[j] = ((const float4*)(centers + (size_t)i * DD))[j];
    __syncthreads();

    float ss = 0.f;
    const float4* cj = (const float4*)(centers + (size_t)j * DD);
    #pragma unroll
    for (int q = 0; q < 16; q++) {
        float4 u = cj[q];
        float e0 = u.x - rowi[q*4+0], e1 = u.y - rowi[q*4+1];
        float e2 = u.z - rowi[q*4+2], e3 = u.w - rowi[q*4+3];
        ss += e0*e0 + e1*e1 + e2*e2 + e3*e3;
    }
    float dist = (i != j && ss > 0.f) ? sqrtf(ss) : 0.f;

    #pragma unroll
    for (int d = 1; d < 64; d <<= 1) dist += __shfl_xor(dist, d, 64);
    if (j == 0) atomicAdd(&ws[192], dist);
}

__global__ void aux_fin(const float* __restrict__ ws, float* __restrict__ out, int B)
{
    const int k = threadIdx.x;  // 64 threads
    const float uni = 1.0f / 64.0f;

    float p   = ws[k] / (float)B;
    float bal = uni * (logf(uni) - logf(p + 1e-8f));

    float cnt = ws[128 + k];
    float ne  = cnt > 0.f ? 1.f : 0.f;
    float pcm = ne * (ws[64 + k] / fmaxf(cnt, 1.f));
    float ps  = p;

    #pragma unroll
    for (int d = 1; d < 64; d <<= 1) {
        bal += __shfl_xor(bal, d, 64);
        ne  += __shfl_xor(ne,  d, 64);
        pcm += __shfl_xor(pcm, d, 64);
        ps  += __shfl_xor(ps,  d, 64);
    }

    float comp = pcm / fmaxf(ne, 1.f);
    float pm   = ps * (1.0f / 64.0f);
    float dv   = (p - pm) * (p - pm);
    #pragma unroll
    for (int d = 1; d < 64; d <<= 1) dv += __shfl_xor(dv, d, 64);
    float stdv = sqrtf(dv / 63.0f);

    float sep = -ws[192] / (64.0f * 63.0f);

    if (k == 0) {
        out[0] = 0.1f * bal + 0.1f * sep + 0.1f * comp;
        out[1] = bal;
        out[2] = sep;
        out[3] = comp;
        out[4] = stdv;
    }
}

extern "C" void kernel_launch(void* const* d_in, const int* in_sizes, int n_in,
                              void* d_out, int out_size, void* d_ws, size_t ws_size,
                              hipStream_t stream) {
    const float* z       = (const float*)d_in[0];
    const float* assign  = (const float*)d_in[1];
    const float* centers = (const float*)d_in[2];
    float* ws = (float*)d_ws;
    const int B = in_sizes[0] / DD;

    hipMemsetAsync(d_ws, 0, 1024, stream);
    aux_sep<<<64, 64, 0, stream>>>(centers, ws);
    aux_main<<<2048, 256, 0, stream>>>(z, assign, centers, ws, B);
    aux_fin<<<1, 64, 0, stream>>>(ws, (float*)d_out, B);
}